// Round 4
// baseline (193.057 us; speedup 1.0000x reference)
//
#include <hip/hip_runtime.h>
#include <cstdint>
#include <cstddef>

// BasicViTNCA3D: 24^3 cells, C=128, 8 heads x dim16, MLP 512, 2 NCA steps.
// 4 dispatches: packAll, k1 (pe+LN1+qkv, step0), kA x2 (attn..update + next-qkv tail).
// GEMMs bf16 MFMA 16x16x32; qkv bf16 double-buffered; residual stream fp32.
#define NCELL 13824

typedef short bf16x8 __attribute__((ext_vector_type(8)));  // 8 bf16 (4 VGPRs)
typedef float f32x4  __attribute__((ext_vector_type(4)));  // MFMA acc

__device__ __forceinline__ unsigned short f2bf(float x) {
  union { float f; uint32_t u; } c; c.f = x;
  uint32_t r = c.u + 0x7fffu + ((c.u >> 16) & 1u);  // RNE
  return (unsigned short)(r >> 16);
}
// 4 consecutive bf16 -> 4 floats (one 8B load)
__device__ __forceinline__ void bf4_to_f(const unsigned short* p, float* f) {
  uint2 v = *(const uint2*)p;
  union { uint32_t u; float x; } c;
  c.u = v.x << 16; f[0] = c.x;  c.u = v.x & 0xffff0000u; f[1] = c.x;
  c.u = v.y << 16; f[2] = c.x;  c.u = v.y & 0xffff0000u; f[3] = c.x;
}

// A-fragment (16x32 tile, row = lane&15, k = (lane>>4)*8+j) from fp32 LDS row
__device__ __forceinline__ bf16x8 afrag_f32(const float* p) {
  float4 u0 = *(const float4*)p;
  float4 u1 = *(const float4*)(p + 4);
  bf16x8 a;
  a[0] = (short)f2bf(u0.x); a[1] = (short)f2bf(u0.y);
  a[2] = (short)f2bf(u0.z); a[3] = (short)f2bf(u0.w);
  a[4] = (short)f2bf(u1.x); a[5] = (short)f2bf(u1.y);
  a[6] = (short)f2bf(u1.z); a[7] = (short)f2bf(u1.w);
  return a;
}

// ---------------- Threefry-2x32 (JAX-compatible) ----------------
__device__ __forceinline__ void tf2x32(uint32_t k0, uint32_t k1,
                                       uint32_t x0, uint32_t x1,
                                       uint32_t& o0, uint32_t& o1) {
  uint32_t k2 = k0 ^ k1 ^ 0x1BD11BDAu;
  x0 += k0; x1 += k1;
#define TFR(r) { x0 += x1; x1 = (x1 << (r)) | (x1 >> (32 - (r))); x1 ^= x0; }
  TFR(13) TFR(15) TFR(26) TFR(6)   x0 += k1; x1 += k2 + 1u;
  TFR(17) TFR(29) TFR(16) TFR(24)  x0 += k2; x1 += k0 + 2u;
  TFR(13) TFR(15) TFR(26) TFR(6)   x0 += k0; x1 += k1 + 3u;
  TFR(17) TFR(29) TFR(16) TFR(24)  x0 += k1; x1 += k2 + 4u;
  TFR(13) TFR(15) TFR(26) TFR(6)   x0 += k2; x1 += k0 + 5u;
#undef TFR
  o0 = x0; o1 = x1;
}

__device__ __forceinline__ float pe_val(int n, int c) {
  int dd = n % 24, ww = (n / 24) % 24, hh = n / 576;
  if (c == 126)
    return sinf((float)hh) + sinf(0.01f * (float)ww) + sinf(0.0001f * (float)dd);
  return cosf((float)hh) + cosf(0.01f * (float)ww) + cosf(0.0001f * (float)dd);
}

// ---------------- packAll: 5 weights -> MFMA B-frag bf16 ----------------
__device__ __forceinline__ void packOne(const float* __restrict__ W, int K, int N,
                                        unsigned short* __restrict__ P, int f) {
  int KT = K >> 5;
  int lane = f & 63;
  int ft = f >> 6;
  int kt = ft % KT, nt = ft / KT;
  int col = nt * 16 + (lane & 15);
  int k0 = kt * 32 + (lane >> 4) * 8;
  uint32_t w[4];
  #pragma unroll
  for (int p = 0; p < 4; ++p) {
    uint32_t lo = f2bf(W[(size_t)(k0 + 2 * p) * N + col]);
    uint32_t hi = f2bf(W[(size_t)(k0 + 2 * p + 1) * N + col]);
    w[p] = lo | (hi << 16);
  }
  uint4 v; v.x = w[0]; v.y = w[1]; v.z = w[2]; v.w = w[3];
  ((uint4*)P)[f] = v;
}

__global__ __launch_bounds__(256) void packAll(
    const float* __restrict__ Wqkv, const float* __restrict__ Wout,
    const float* __restrict__ Wff1, const float* __restrict__ Wff2,
    const float* __restrict__ Whead,
    unsigned short* __restrict__ pQkv, unsigned short* __restrict__ pOut,
    unsigned short* __restrict__ pFF1, unsigned short* __restrict__ pFF2,
    unsigned short* __restrict__ pHead) {
  int f = blockIdx.x * 256 + threadIdx.x;
  if (f < 6144)        packOne(Wqkv, 128, 384, pQkv, f);
  else if (f < 8192)   packOne(Wout, 128, 128, pOut, f - 6144);
  else if (f < 16384)  packOne(Wff1, 128, 512, pFF1, f - 8192);
  else if (f < 24576)  packOne(Wff2, 512, 128, pFF2, f - 16384);
  else if (f < 26624)  packOne(Whead, 128, 128, pHead, f - 24576);
}

// ---------------- K1: pe + LN1 + qkv GEMM (step 0 only) ----------------
__global__ __launch_bounds__(256) void nca_k1(
    const float* __restrict__ x, const float* __restrict__ ln1s,
    const float* __restrict__ ln1b, const unsigned short* __restrict__ pQkv,
    unsigned short* __restrict__ wqkv,
    const int* __restrict__ steps, int s) {
  if (s >= *steps) return;
  __shared__ float ly[16][132];
  __shared__ float lmean[16], lrstd[16];
  const int t = threadIdx.x;
  const int swz = (blockIdx.x & 7) * 108 + (blockIdx.x >> 3);  // XCD-contiguous
  const int base = swz * 16;
  #pragma unroll
  for (int i = 0; i < 8; ++i) {
    int idx = i * 256 + t;
    int r = idx >> 7, c = idx & 127;
    int n = base + r;
    ly[r][c] = (c < 126) ? x[(size_t)n * 128 + c] : pe_val(n, c);
  }
  __syncthreads();
  { int r = t >> 4, j = t & 15;
    float s1 = 0.f, s2 = 0.f;
    #pragma unroll
    for (int cc = 0; cc < 8; ++cc) { float v = ly[r][j * 8 + cc]; s1 += v; s2 += v * v; }
    #pragma unroll
    for (int off = 1; off < 16; off <<= 1) { s1 += __shfl_xor(s1, off); s2 += __shfl_xor(s2, off); }
    if (j == 0) {
      float m = s1 * (1.f / 128.f);
      float var = s2 * (1.f / 128.f) - m * m;
      lmean[r] = m; lrstd[r] = rsqrtf(var + 1e-5f);
    }
  }
  __syncthreads();
  #pragma unroll
  for (int i = 0; i < 8; ++i) {
    int idx = i * 256 + t;
    int r = idx >> 7, c = idx & 127;
    ly[r][c] = (ly[r][c] - lmean[r]) * lrstd[r] * ln1s[c] + ln1b[c];
  }
  __syncthreads();
  const int w = t >> 6, l = t & 63;
  bf16x8 a4[4];
  #pragma unroll
  for (int kt = 0; kt < 4; ++kt)
    a4[kt] = afrag_f32(&ly[l & 15][kt * 32 + (l >> 4) * 8]);
  f32x4 acc[6];
  #pragma unroll
  for (int q = 0; q < 6; ++q) acc[q] = (f32x4){0.f, 0.f, 0.f, 0.f};
  const bf16x8* B = (const bf16x8*)pQkv;
  #pragma unroll
  for (int kt = 0; kt < 4; ++kt) {
    #pragma unroll
    for (int q = 0; q < 6; ++q) {
      int nt = w * 6 + q;
      acc[q] = __builtin_amdgcn_mfma_f32_16x16x32_bf16(a4[kt], B[(nt * 4 + kt) * 64 + l], acc[q], 0, 0, 0);
    }
  }
  #pragma unroll
  for (int q = 0; q < 6; ++q) {
    int col = (w * 6 + q) * 16 + (l & 15);
    #pragma unroll
    for (int j = 0; j < 4; ++j)
      wqkv[(size_t)(base + (l >> 4) * 4 + j) * 384 + col] = f2bf(acc[q][j]);
  }
}

// ---- kA: attn + out-proj + LN2 + FF1 + FF2 + LN3 + head + mask-update + next qkv ----
__global__ __launch_bounds__(512, 6) void nca_kA(
    const unsigned short* __restrict__ qkv, unsigned short* __restrict__ qkvN,
    const unsigned short* __restrict__ pQkv,
    const unsigned short* __restrict__ pOut, const float* __restrict__ bout,
    const float* __restrict__ ln1s, const float* __restrict__ ln1b,
    const float* __restrict__ ln2s, const float* __restrict__ ln2b,
    const unsigned short* __restrict__ pFF1, const float* __restrict__ bff1,
    const unsigned short* __restrict__ pFF2, const float* __restrict__ bff2,
    const float* __restrict__ ln3s, const float* __restrict__ ln3b,
    const unsigned short* __restrict__ pHead, const float* __restrict__ bhead,
    const float* __restrict__ xin, float* __restrict__ xout,
    const int* __restrict__ steps, int s) {
  if (s >= *steps) return;
  __shared__ float lbuf[16][132];           // attn-out -> ln2 -> y3 -> ln3 -> ln1'
  __shared__ float ly2[16][132];            // y2 residual, then x_new (for tail)
  __shared__ unsigned short lh[16][520];    // GELU(FF1) bf16
  __shared__ float lmean[16], lrstd[16], lmask[16];
  const int t = threadIdx.x;
  const int swz = (blockIdx.x & 7) * 108 + (blockIdx.x >> 3);  // XCD-contiguous
  const int base = swz * 16;
  const int w = t >> 6, l = t & 63;
  const int lr = (l >> 4) * 4, lc = l & 15;

  if (t < 16) { // JAX threefry per-cell mask (partitionable random_bits)
    uint32_t kk0, kk1, b0, b1;
    tf2x32(0u, 42u, 0u, (uint32_t)s, kk0, kk1);
    tf2x32(kk0, kk1, 0u, (uint32_t)(base + t), b0, b1);
    uint32_t bits = b0 ^ b1;
    lmask[t] = ((bits >> 9) > 0x400000u) ? 1.0f : 0.0f;
  }
  // ---- attention: 16 cells x 8 heads x 4 quarters = 512 threads ----
  {
    const int cell = t >> 5, head = (t >> 2) & 7, qr = t & 3;
    const int n = base + cell;
    const int dd = n % 24, ww = (n / 24) % 24, hh = n / 576;
    float qf[4];
    bf4_to_f(qkv + (size_t)n * 384 + head * 16 + qr * 4, qf);
    float logits[27];
    int idx = 0;
    #pragma unroll
    for (int di = -1; di <= 1; ++di)
    #pragma unroll
    for (int dj = -1; dj <= 1; ++dj)
    #pragma unroll
    for (int dk = -1; dk <= 1; ++dk) {
      int h2 = hh + di, w2 = ww + dj, d2 = dd + dk;
      bool ok = ((unsigned)h2 < 24u) && ((unsigned)w2 < 24u) && ((unsigned)d2 < 24u);
      float dot = 0.f;
      if (ok) {
        float kf[4];
        bf4_to_f(qkv + (size_t)((h2 * 24 + w2) * 24 + d2) * 384 + 128 + head * 16 + qr * 4, kf);
        dot = qf[0] * kf[0] + qf[1] * kf[1] + qf[2] * kf[2] + qf[3] * kf[3];
      }
      dot += __shfl_xor(dot, 1);
      dot += __shfl_xor(dot, 2);            // full 16-ch dot in all 4 lanes
      logits[idx++] = dot * 0.25f;          // OOB -> logit 0 (zero-padded localize)
    }
    float m = logits[0];
    #pragma unroll
    for (int j = 1; j < 27; ++j) m = fmaxf(m, logits[j]);
    float den = 0.f;
    #pragma unroll
    for (int j = 0; j < 27; ++j) { logits[j] = expf(logits[j] - m); den += logits[j]; }
    float av[4] = {0.f, 0.f, 0.f, 0.f};
    idx = 0;
    #pragma unroll
    for (int di = -1; di <= 1; ++di)
    #pragma unroll
    for (int dj = -1; dj <= 1; ++dj)
    #pragma unroll
    for (int dk = -1; dk <= 1; ++dk) {
      int h2 = hh + di, w2 = ww + dj, d2 = dd + dk;
      bool ok = ((unsigned)h2 < 24u) && ((unsigned)w2 < 24u) && ((unsigned)d2 < 24u);
      if (ok) {
        float vf[4];
        bf4_to_f(qkv + (size_t)((h2 * 24 + w2) * 24 + d2) * 384 + 256 + head * 16 + qr * 4, vf);
        float wgt = logits[idx];
        av[0] += wgt * vf[0]; av[1] += wgt * vf[1];
        av[2] += wgt * vf[2]; av[3] += wgt * vf[3];
      }
      ++idx;
    }
    float inv = 1.f / den;
    float4 r4; r4.x = av[0]*inv; r4.y = av[1]*inv; r4.z = av[2]*inv; r4.w = av[3]*inv;
    *(float4*)&lbuf[cell][head * 16 + qr * 4] = r4;
  }
  __syncthreads();
  // ---- out-proj: wave w -> coltile w (N=128) ----
  bf16x8 a4[4];
  #pragma unroll
  for (int kt = 0; kt < 4; ++kt)
    a4[kt] = afrag_f32(&lbuf[l & 15][kt * 32 + (l >> 4) * 8]);
  float xres[4];
  {
    f32x4 acc = (f32x4){0.f,0.f,0.f,0.f};
    const bf16x8* B = (const bf16x8*)pOut;
    #pragma unroll
    for (int kt = 0; kt < 4; ++kt)
      acc = __builtin_amdgcn_mfma_f32_16x16x32_bf16(a4[kt], B[(w * 4 + kt) * 64 + l], acc, 0, 0, 0);
    int col = w * 16 + lc;
    #pragma unroll
    for (int j = 0; j < 4; ++j) {
      int r = lr + j, n = base + r;
      xres[j] = xin[(size_t)n * 128 + col];                 // true x (for final update)
      float resy = (col < 126) ? xres[j] : pe_val(n, col);  // y residual has pe
      ly2[r][col] = acc[j] + bout[col] + resy;
    }
  }
  __syncthreads();
  { // LN2 stats: 32 thr/row, 4 ch each
    int r = t >> 5, j = t & 31;
    float s1 = 0.f, s2 = 0.f;
    #pragma unroll
    for (int cc = 0; cc < 4; ++cc) { float v = ly2[r][j * 4 + cc]; s1 += v; s2 += v * v; }
    #pragma unroll
    for (int off = 1; off < 32; off <<= 1) { s1 += __shfl_xor(s1, off); s2 += __shfl_xor(s2, off); }
    if (j == 0) {
      float m = s1 * (1.f / 128.f);
      float var = s2 * (1.f / 128.f) - m * m;
      lmean[r] = m; lrstd[r] = rsqrtf(var + 1e-5f);
    }
  }
  __syncthreads();
  #pragma unroll
  for (int i = 0; i < 4; ++i) {
    int idx = i * 512 + t;
    int r = idx >> 7, c = idx & 127;
    lbuf[r][c] = (ly2[r][c] - lmean[r]) * lrstd[r] * ln2s[c] + ln2b[c];
  }
  __syncthreads();
  // ---- FF1: wave w -> coltiles w*4..w*4+3 (N=512); GELU -> lh bf16 ----
  #pragma unroll
  for (int kt = 0; kt < 4; ++kt)
    a4[kt] = afrag_f32(&lbuf[l & 15][kt * 32 + (l >> 4) * 8]);
  {
    f32x4 acc[4];
    #pragma unroll
    for (int q = 0; q < 4; ++q) acc[q] = (f32x4){0.f,0.f,0.f,0.f};
    const bf16x8* B = (const bf16x8*)pFF1;
    #pragma unroll
    for (int kt = 0; kt < 4; ++kt) {
      #pragma unroll
      for (int q = 0; q < 4; ++q) {
        int nt = w * 4 + q;
        acc[q] = __builtin_amdgcn_mfma_f32_16x16x32_bf16(a4[kt], B[(nt * 4 + kt) * 64 + l], acc[q], 0, 0, 0);
      }
    }
    #pragma unroll
    for (int q = 0; q < 4; ++q) {
      int col = (w * 4 + q) * 16 + lc;
      #pragma unroll
      for (int j = 0; j < 4; ++j) {
        float v = acc[q][j] + bff1[col];
        v = 0.5f * v * (1.f + erff(v * 0.70710678118654752f));
        lh[lr + j][col] = f2bf(v);
      }
    }
  }
  __syncthreads();
  // ---- FF2: K=512, wave w -> coltile w; y3 = acc + b + y2 -> lbuf ----
  {
    f32x4 acc = (f32x4){0.f,0.f,0.f,0.f};
    const bf16x8* B = (const bf16x8*)pFF2;
    #pragma unroll
    for (int kt = 0; kt < 16; ++kt) {
      bf16x8 a = *(const bf16x8*)&lh[l & 15][kt * 32 + (l >> 4) * 8];
      acc = __builtin_amdgcn_mfma_f32_16x16x32_bf16(a, B[(w * 16 + kt) * 64 + l], acc, 0, 0, 0);
    }
    int col = w * 16 + lc;
    #pragma unroll
    for (int j = 0; j < 4; ++j) {
      int r = lr + j;
      lbuf[r][col] = acc[j] + bff2[col] + ly2[r][col];
    }
  }
  __syncthreads();
  { // LN3 stats
    int r = t >> 5, j = t & 31;
    float s1 = 0.f, s2 = 0.f;
    #pragma unroll
    for (int cc = 0; cc < 4; ++cc) { float v = lbuf[r][j * 4 + cc]; s1 += v; s2 += v * v; }
    #pragma unroll
    for (int off = 1; off < 32; off <<= 1) { s1 += __shfl_xor(s1, off); s2 += __shfl_xor(s2, off); }
    if (j == 0) {
      float m = s1 * (1.f / 128.f);
      float var = s2 * (1.f / 128.f) - m * m;
      lmean[r] = m; lrstd[r] = rsqrtf(var + 1e-5f);
    }
  }
  __syncthreads();
  #pragma unroll
  for (int i = 0; i < 4; ++i) {   // in-place normalize (each elem owned by one thread)
    int idx = i * 512 + t;
    int r = idx >> 7, c = idx & 127;
    lbuf[r][c] = (lbuf[r][c] - lmean[r]) * lrstd[r] * ln3s[c] + ln3b[c];
  }
  __syncthreads();
  // ---- head: wave w -> coltile w; dx; masked update; stash x_new in ly2 ----
  #pragma unroll
  for (int kt = 0; kt < 4; ++kt)
    a4[kt] = afrag_f32(&lbuf[l & 15][kt * 32 + (l >> 4) * 8]);
  {
    f32x4 acc = (f32x4){0.f,0.f,0.f,0.f};
    const bf16x8* B = (const bf16x8*)pHead;
    #pragma unroll
    for (int kt = 0; kt < 4; ++kt)
      acc = __builtin_amdgcn_mfma_f32_16x16x32_bf16(a4[kt], B[(w * 4 + kt) * 64 + l], acc, 0, 0, 0);
    int col = w * 16 + lc;
    #pragma unroll
    for (int j = 0; j < 4; ++j) {
      int r = lr + j;
      size_t n = base + r;
      float dx = acc[j] + bhead[col];
      float xn = xres[j] + dx * lmask[r];
      xout[n * 128 + col] = xn;
      ly2[r][col] = xn;
    }
  }
  // ---- tail: next step's pe + LN1 + qkv GEMM (skipped on last step) ----
  if (s + 1 < *steps) {
    __syncthreads();
    if (t < 32) { int r = t >> 1, c = 126 + (t & 1); ly2[r][c] = pe_val(base + r, c); }
    __syncthreads();
    { // LN1 stats
      int r = t >> 5, j = t & 31;
      float s1 = 0.f, s2 = 0.f;
      #pragma unroll
      for (int cc = 0; cc < 4; ++cc) { float v = ly2[r][j * 4 + cc]; s1 += v; s2 += v * v; }
      #pragma unroll
      for (int off = 1; off < 32; off <<= 1) { s1 += __shfl_xor(s1, off); s2 += __shfl_xor(s2, off); }
      if (j == 0) {
        float m = s1 * (1.f / 128.f);
        float var = s2 * (1.f / 128.f) - m * m;
        lmean[r] = m; lrstd[r] = rsqrtf(var + 1e-5f);
      }
    }
    __syncthreads();
    #pragma unroll
    for (int i = 0; i < 4; ++i) {
      int idx = i * 512 + t;
      int r = idx >> 7, c = idx & 127;
      lbuf[r][c] = (ly2[r][c] - lmean[r]) * lrstd[r] * ln1s[c] + ln1b[c];
    }
    __syncthreads();
    #pragma unroll
    for (int kt = 0; kt < 4; ++kt)
      a4[kt] = afrag_f32(&lbuf[l & 15][kt * 32 + (l >> 4) * 8]);
    const bf16x8* B = (const bf16x8*)pQkv;
    #pragma unroll
    for (int q = 0; q < 3; ++q) {
      f32x4 acc = (f32x4){0.f,0.f,0.f,0.f};
      int nt = w * 3 + q;
      #pragma unroll
      for (int kt = 0; kt < 4; ++kt)
        acc = __builtin_amdgcn_mfma_f32_16x16x32_bf16(a4[kt], B[(nt * 4 + kt) * 64 + l], acc, 0, 0, 0);
      int col = nt * 16 + lc;
      #pragma unroll
      for (int j = 0; j < 4; ++j)
        qkvN[(size_t)(base + lr + j) * 384 + col] = f2bf(acc[j]);
    }
  }
}

extern "C" void kernel_launch(void* const* d_in, const int* in_sizes, int n_in,
                              void* d_out, int out_size, void* d_ws, size_t ws_size,
                              hipStream_t stream) {
  const float* x0   = (const float*)d_in[0];
  const float* Wqkv = (const float*)d_in[1];
  const float* Wout = (const float*)d_in[2];
  const float* bout = (const float*)d_in[3];
  const float* ln1s = (const float*)d_in[4];
  const float* ln1b = (const float*)d_in[5];
  const float* Wff1 = (const float*)d_in[6];
  const float* bff1 = (const float*)d_in[7];
  const float* Wff2 = (const float*)d_in[8];
  const float* bff2 = (const float*)d_in[9];
  const float* ln2s = (const float*)d_in[10];
  const float* ln2b = (const float*)d_in[11];
  const float* ln3s = (const float*)d_in[12];
  const float* ln3b = (const float*)d_in[13];
  const float* Whead= (const float*)d_in[14];
  const float* bhead= (const float*)d_in[15];
  const int*   steps= (const int*)d_in[16];
  float* out = (float*)d_out;

  unsigned short* qkvA = (unsigned short*)d_ws;          // N*384 bf16
  unsigned short* qkvB = qkvA + (size_t)NCELL * 384;     // N*384 bf16
  unsigned short* pQkv = qkvB + (size_t)NCELL * 384;
  unsigned short* pOut = pQkv + 128 * 384;
  unsigned short* pFF1 = pOut + 128 * 128;
  unsigned short* pFF2 = pFF1 + 128 * 512;
  unsigned short* pHead= pFF2 + 512 * 128;

  packAll<<<dim3(104), dim3(256), 0, stream>>>(Wqkv, Wout, Wff1, Wff2, Whead,
                                               pQkv, pOut, pFF1, pFF2, pHead);
  nca_k1<<<dim3(864), dim3(256), 0, stream>>>(x0, ln1s, ln1b, pQkv, qkvA, steps, 0);
  // s=0: read qkvA, write next-step qkvB; s=1: read qkvB (tail skipped)
  nca_kA<<<dim3(864), dim3(512), 0, stream>>>(qkvA, qkvB, pQkv, pOut, bout,
                                              ln1s, ln1b, ln2s, ln2b, pFF1, bff1,
                                              pFF2, bff2, ln3s, ln3b, pHead, bhead,
                                              x0, out, steps, 0);
  nca_kA<<<dim3(864), dim3(512), 0, stream>>>(qkvB, qkvA, pQkv, pOut, bout,
                                              ln1s, ln1b, ln2s, ln2b, pFF1, bff1,
                                              pFF2, bff2, ln3s, ln3b, pHead, bhead,
                                              out, out, steps, 1);
}

// Round 5
// 145.948 us; speedup vs baseline: 1.3228x; 1.3228x over previous
//
#include <hip/hip_runtime.h>
#include <cstdint>
#include <cstddef>

// BasicViTNCA3D: 24^3 cells, C=128, 8 heads x dim16, MLP 512, 2 NCA steps.
// 4 dispatches: packAll, k1 (pe+LN1+qkv, step0), kA x2 (attn..update + next-qkv tail).
// GEMMs bf16 MFMA 16x16x32; qkv bf16 double-buffered; residual stream fp32.
// R5: __launch_bounds__(512,4) — R4's (512,6) capped VGPR at 40 and spilled
// logits[27] to scratch (WRITE_SIZE 6.9->92.7 MB). Cap 128 removes the spill.
#define NCELL 13824

typedef short bf16x8 __attribute__((ext_vector_type(8)));  // 8 bf16 (4 VGPRs)
typedef float f32x4  __attribute__((ext_vector_type(4)));  // MFMA acc

__device__ __forceinline__ unsigned short f2bf(float x) {
  union { float f; uint32_t u; } c; c.f = x;
  uint32_t r = c.u + 0x7fffu + ((c.u >> 16) & 1u);  // RNE
  return (unsigned short)(r >> 16);
}
// 4 consecutive bf16 -> 4 floats (one 8B load)
__device__ __forceinline__ void bf4_to_f(const unsigned short* p, float* f) {
  uint2 v = *(const uint2*)p;
  union { uint32_t u; float x; } c;
  c.u = v.x << 16; f[0] = c.x;  c.u = v.x & 0xffff0000u; f[1] = c.x;
  c.u = v.y << 16; f[2] = c.x;  c.u = v.y & 0xffff0000u; f[3] = c.x;
}

// A-fragment (16x32 tile, row = lane&15, k = (lane>>4)*8+j) from fp32 LDS row
__device__ __forceinline__ bf16x8 afrag_f32(const float* p) {
  float4 u0 = *(const float4*)p;
  float4 u1 = *(const float4*)(p + 4);
  bf16x8 a;
  a[0] = (short)f2bf(u0.x); a[1] = (short)f2bf(u0.y);
  a[2] = (short)f2bf(u0.z); a[3] = (short)f2bf(u0.w);
  a[4] = (short)f2bf(u1.x); a[5] = (short)f2bf(u1.y);
  a[6] = (short)f2bf(u1.z); a[7] = (short)f2bf(u1.w);
  return a;
}

// ---------------- Threefry-2x32 (JAX-compatible) ----------------
__device__ __forceinline__ void tf2x32(uint32_t k0, uint32_t k1,
                                       uint32_t x0, uint32_t x1,
                                       uint32_t& o0, uint32_t& o1) {
  uint32_t k2 = k0 ^ k1 ^ 0x1BD11BDAu;
  x0 += k0; x1 += k1;
#define TFR(r) { x0 += x1; x1 = (x1 << (r)) | (x1 >> (32 - (r))); x1 ^= x0; }
  TFR(13) TFR(15) TFR(26) TFR(6)   x0 += k1; x1 += k2 + 1u;
  TFR(17) TFR(29) TFR(16) TFR(24)  x0 += k2; x1 += k0 + 2u;
  TFR(13) TFR(15) TFR(26) TFR(6)   x0 += k0; x1 += k1 + 3u;
  TFR(17) TFR(29) TFR(16) TFR(24)  x0 += k1; x1 += k2 + 4u;
  TFR(13) TFR(15) TFR(26) TFR(6)   x0 += k2; x1 += k0 + 5u;
#undef TFR
  o0 = x0; o1 = x1;
}

__device__ __forceinline__ float pe_val(int n, int c) {
  int dd = n % 24, ww = (n / 24) % 24, hh = n / 576;
  if (c == 126)
    return sinf((float)hh) + sinf(0.01f * (float)ww) + sinf(0.0001f * (float)dd);
  return cosf((float)hh) + cosf(0.01f * (float)ww) + cosf(0.0001f * (float)dd);
}

// ---------------- packAll: 5 weights -> MFMA B-frag bf16 ----------------
__device__ __forceinline__ void packOne(const float* __restrict__ W, int K, int N,
                                        unsigned short* __restrict__ P, int f) {
  int KT = K >> 5;
  int lane = f & 63;
  int ft = f >> 6;
  int kt = ft % KT, nt = ft / KT;
  int col = nt * 16 + (lane & 15);
  int k0 = kt * 32 + (lane >> 4) * 8;
  uint32_t w[4];
  #pragma unroll
  for (int p = 0; p < 4; ++p) {
    uint32_t lo = f2bf(W[(size_t)(k0 + 2 * p) * N + col]);
    uint32_t hi = f2bf(W[(size_t)(k0 + 2 * p + 1) * N + col]);
    w[p] = lo | (hi << 16);
  }
  uint4 v; v.x = w[0]; v.y = w[1]; v.z = w[2]; v.w = w[3];
  ((uint4*)P)[f] = v;
}

__global__ __launch_bounds__(256) void packAll(
    const float* __restrict__ Wqkv, const float* __restrict__ Wout,
    const float* __restrict__ Wff1, const float* __restrict__ Wff2,
    const float* __restrict__ Whead,
    unsigned short* __restrict__ pQkv, unsigned short* __restrict__ pOut,
    unsigned short* __restrict__ pFF1, unsigned short* __restrict__ pFF2,
    unsigned short* __restrict__ pHead) {
  int f = blockIdx.x * 256 + threadIdx.x;
  if (f < 6144)        packOne(Wqkv, 128, 384, pQkv, f);
  else if (f < 8192)   packOne(Wout, 128, 128, pOut, f - 6144);
  else if (f < 16384)  packOne(Wff1, 128, 512, pFF1, f - 8192);
  else if (f < 24576)  packOne(Wff2, 512, 128, pFF2, f - 16384);
  else if (f < 26624)  packOne(Whead, 128, 128, pHead, f - 24576);
}

// ---------------- K1: pe + LN1 + qkv GEMM (step 0 only) ----------------
__global__ __launch_bounds__(256) void nca_k1(
    const float* __restrict__ x, const float* __restrict__ ln1s,
    const float* __restrict__ ln1b, const unsigned short* __restrict__ pQkv,
    unsigned short* __restrict__ wqkv,
    const int* __restrict__ steps, int s) {
  if (s >= *steps) return;
  __shared__ float ly[16][132];
  __shared__ float lmean[16], lrstd[16];
  const int t = threadIdx.x;
  const int swz = (blockIdx.x & 7) * 108 + (blockIdx.x >> 3);  // XCD-contiguous
  const int base = swz * 16;
  #pragma unroll
  for (int i = 0; i < 8; ++i) {
    int idx = i * 256 + t;
    int r = idx >> 7, c = idx & 127;
    int n = base + r;
    ly[r][c] = (c < 126) ? x[(size_t)n * 128 + c] : pe_val(n, c);
  }
  __syncthreads();
  { int r = t >> 4, j = t & 15;
    float s1 = 0.f, s2 = 0.f;
    #pragma unroll
    for (int cc = 0; cc < 8; ++cc) { float v = ly[r][j * 8 + cc]; s1 += v; s2 += v * v; }
    #pragma unroll
    for (int off = 1; off < 16; off <<= 1) { s1 += __shfl_xor(s1, off); s2 += __shfl_xor(s2, off); }
    if (j == 0) {
      float m = s1 * (1.f / 128.f);
      float var = s2 * (1.f / 128.f) - m * m;
      lmean[r] = m; lrstd[r] = rsqrtf(var + 1e-5f);
    }
  }
  __syncthreads();
  #pragma unroll
  for (int i = 0; i < 8; ++i) {
    int idx = i * 256 + t;
    int r = idx >> 7, c = idx & 127;
    ly[r][c] = (ly[r][c] - lmean[r]) * lrstd[r] * ln1s[c] + ln1b[c];
  }
  __syncthreads();
  const int w = t >> 6, l = t & 63;
  bf16x8 a4[4];
  #pragma unroll
  for (int kt = 0; kt < 4; ++kt)
    a4[kt] = afrag_f32(&ly[l & 15][kt * 32 + (l >> 4) * 8]);
  f32x4 acc[6];
  #pragma unroll
  for (int q = 0; q < 6; ++q) acc[q] = (f32x4){0.f, 0.f, 0.f, 0.f};
  const bf16x8* B = (const bf16x8*)pQkv;
  #pragma unroll
  for (int kt = 0; kt < 4; ++kt) {
    #pragma unroll
    for (int q = 0; q < 6; ++q) {
      int nt = w * 6 + q;
      acc[q] = __builtin_amdgcn_mfma_f32_16x16x32_bf16(a4[kt], B[(nt * 4 + kt) * 64 + l], acc[q], 0, 0, 0);
    }
  }
  #pragma unroll
  for (int q = 0; q < 6; ++q) {
    int col = (w * 6 + q) * 16 + (l & 15);
    #pragma unroll
    for (int j = 0; j < 4; ++j)
      wqkv[(size_t)(base + (l >> 4) * 4 + j) * 384 + col] = f2bf(acc[q][j]);
  }
}

// ---- kA: attn + out-proj + LN2 + FF1 + FF2 + LN3 + head + mask-update + next qkv ----
__global__ __launch_bounds__(512, 4) void nca_kA(
    const unsigned short* __restrict__ qkv, unsigned short* __restrict__ qkvN,
    const unsigned short* __restrict__ pQkv,
    const unsigned short* __restrict__ pOut, const float* __restrict__ bout,
    const float* __restrict__ ln1s, const float* __restrict__ ln1b,
    const float* __restrict__ ln2s, const float* __restrict__ ln2b,
    const unsigned short* __restrict__ pFF1, const float* __restrict__ bff1,
    const unsigned short* __restrict__ pFF2, const float* __restrict__ bff2,
    const float* __restrict__ ln3s, const float* __restrict__ ln3b,
    const unsigned short* __restrict__ pHead, const float* __restrict__ bhead,
    const float* __restrict__ xin, float* __restrict__ xout,
    const int* __restrict__ steps, int s) {
  if (s >= *steps) return;
  __shared__ float lbuf[16][132];           // attn-out -> ln2 -> y3 -> ln3 -> ln1'
  __shared__ float ly2[16][132];            // y2 residual, then x_new (for tail)
  __shared__ unsigned short lh[16][520];    // GELU(FF1) bf16
  __shared__ float lmean[16], lrstd[16], lmask[16];
  const int t = threadIdx.x;
  const int swz = (blockIdx.x & 7) * 108 + (blockIdx.x >> 3);  // XCD-contiguous
  const int base = swz * 16;
  const int w = t >> 6, l = t & 63;
  const int lr = (l >> 4) * 4, lc = l & 15;

  if (t < 16) { // JAX threefry per-cell mask (partitionable random_bits)
    uint32_t kk0, kk1, b0, b1;
    tf2x32(0u, 42u, 0u, (uint32_t)s, kk0, kk1);
    tf2x32(kk0, kk1, 0u, (uint32_t)(base + t), b0, b1);
    uint32_t bits = b0 ^ b1;
    lmask[t] = ((bits >> 9) > 0x400000u) ? 1.0f : 0.0f;
  }
  // ---- attention: 16 cells x 8 heads x 4 quarters = 512 threads ----
  {
    const int cell = t >> 5, head = (t >> 2) & 7, qr = t & 3;
    const int n = base + cell;
    const int dd = n % 24, ww = (n / 24) % 24, hh = n / 576;
    float qf[4];
    bf4_to_f(qkv + (size_t)n * 384 + head * 16 + qr * 4, qf);
    float logits[27];
    int idx = 0;
    #pragma unroll
    for (int di = -1; di <= 1; ++di)
    #pragma unroll
    for (int dj = -1; dj <= 1; ++dj)
    #pragma unroll
    for (int dk = -1; dk <= 1; ++dk) {
      int h2 = hh + di, w2 = ww + dj, d2 = dd + dk;
      bool ok = ((unsigned)h2 < 24u) && ((unsigned)w2 < 24u) && ((unsigned)d2 < 24u);
      float dot = 0.f;
      if (ok) {
        float kf[4];
        bf4_to_f(qkv + (size_t)((h2 * 24 + w2) * 24 + d2) * 384 + 128 + head * 16 + qr * 4, kf);
        dot = qf[0] * kf[0] + qf[1] * kf[1] + qf[2] * kf[2] + qf[3] * kf[3];
      }
      dot += __shfl_xor(dot, 1);
      dot += __shfl_xor(dot, 2);            // full 16-ch dot in all 4 lanes
      logits[idx++] = dot * 0.25f;          // OOB -> logit 0 (zero-padded localize)
    }
    float m = logits[0];
    #pragma unroll
    for (int j = 1; j < 27; ++j) m = fmaxf(m, logits[j]);
    float den = 0.f;
    #pragma unroll
    for (int j = 0; j < 27; ++j) { logits[j] = expf(logits[j] - m); den += logits[j]; }
    float av[4] = {0.f, 0.f, 0.f, 0.f};
    idx = 0;
    #pragma unroll
    for (int di = -1; di <= 1; ++di)
    #pragma unroll
    for (int dj = -1; dj <= 1; ++dj)
    #pragma unroll
    for (int dk = -1; dk <= 1; ++dk) {
      int h2 = hh + di, w2 = ww + dj, d2 = dd + dk;
      bool ok = ((unsigned)h2 < 24u) && ((unsigned)w2 < 24u) && ((unsigned)d2 < 24u);
      if (ok) {
        float vf[4];
        bf4_to_f(qkv + (size_t)((h2 * 24 + w2) * 24 + d2) * 384 + 256 + head * 16 + qr * 4, vf);
        float wgt = logits[idx];
        av[0] += wgt * vf[0]; av[1] += wgt * vf[1];
        av[2] += wgt * vf[2]; av[3] += wgt * vf[3];
      }
      ++idx;
    }
    float inv = 1.f / den;
    float4 r4; r4.x = av[0]*inv; r4.y = av[1]*inv; r4.z = av[2]*inv; r4.w = av[3]*inv;
    *(float4*)&lbuf[cell][head * 16 + qr * 4] = r4;
  }
  __syncthreads();
  // ---- out-proj: wave w -> coltile w (N=128) ----
  bf16x8 a4[4];
  #pragma unroll
  for (int kt = 0; kt < 4; ++kt)
    a4[kt] = afrag_f32(&lbuf[l & 15][kt * 32 + (l >> 4) * 8]);
  float xres[4];
  {
    f32x4 acc = (f32x4){0.f,0.f,0.f,0.f};
    const bf16x8* B = (const bf16x8*)pOut;
    #pragma unroll
    for (int kt = 0; kt < 4; ++kt)
      acc = __builtin_amdgcn_mfma_f32_16x16x32_bf16(a4[kt], B[(w * 4 + kt) * 64 + l], acc, 0, 0, 0);
    int col = w * 16 + lc;
    #pragma unroll
    for (int j = 0; j < 4; ++j) {
      int r = lr + j, n = base + r;
      xres[j] = xin[(size_t)n * 128 + col];                 // true x (for final update)
      float resy = (col < 126) ? xres[j] : pe_val(n, col);  // y residual has pe
      ly2[r][col] = acc[j] + bout[col] + resy;
    }
  }
  __syncthreads();
  { // LN2 stats: 32 thr/row, 4 ch each
    int r = t >> 5, j = t & 31;
    float s1 = 0.f, s2 = 0.f;
    #pragma unroll
    for (int cc = 0; cc < 4; ++cc) { float v = ly2[r][j * 4 + cc]; s1 += v; s2 += v * v; }
    #pragma unroll
    for (int off = 1; off < 32; off <<= 1) { s1 += __shfl_xor(s1, off); s2 += __shfl_xor(s2, off); }
    if (j == 0) {
      float m = s1 * (1.f / 128.f);
      float var = s2 * (1.f / 128.f) - m * m;
      lmean[r] = m; lrstd[r] = rsqrtf(var + 1e-5f);
    }
  }
  __syncthreads();
  #pragma unroll
  for (int i = 0; i < 4; ++i) {
    int idx = i * 512 + t;
    int r = idx >> 7, c = idx & 127;
    lbuf[r][c] = (ly2[r][c] - lmean[r]) * lrstd[r] * ln2s[c] + ln2b[c];
  }
  __syncthreads();
  // ---- FF1: wave w -> coltiles w*4..w*4+3 (N=512); GELU -> lh bf16 ----
  #pragma unroll
  for (int kt = 0; kt < 4; ++kt)
    a4[kt] = afrag_f32(&lbuf[l & 15][kt * 32 + (l >> 4) * 8]);
  {
    f32x4 acc[4];
    #pragma unroll
    for (int q = 0; q < 4; ++q) acc[q] = (f32x4){0.f,0.f,0.f,0.f};
    const bf16x8* B = (const bf16x8*)pFF1;
    #pragma unroll
    for (int kt = 0; kt < 4; ++kt) {
      #pragma unroll
      for (int q = 0; q < 4; ++q) {
        int nt = w * 4 + q;
        acc[q] = __builtin_amdgcn_mfma_f32_16x16x32_bf16(a4[kt], B[(nt * 4 + kt) * 64 + l], acc[q], 0, 0, 0);
      }
    }
    #pragma unroll
    for (int q = 0; q < 4; ++q) {
      int col = (w * 4 + q) * 16 + lc;
      #pragma unroll
      for (int j = 0; j < 4; ++j) {
        float v = acc[q][j] + bff1[col];
        v = 0.5f * v * (1.f + erff(v * 0.70710678118654752f));
        lh[lr + j][col] = f2bf(v);
      }
    }
  }
  __syncthreads();
  // ---- FF2: K=512, wave w -> coltile w; y3 = acc + b + y2 -> lbuf ----
  {
    f32x4 acc = (f32x4){0.f,0.f,0.f,0.f};
    const bf16x8* B = (const bf16x8*)pFF2;
    #pragma unroll
    for (int kt = 0; kt < 16; ++kt) {
      bf16x8 a = *(const bf16x8*)&lh[l & 15][kt * 32 + (l >> 4) * 8];
      acc = __builtin_amdgcn_mfma_f32_16x16x32_bf16(a, B[(w * 16 + kt) * 64 + l], acc, 0, 0, 0);
    }
    int col = w * 16 + lc;
    #pragma unroll
    for (int j = 0; j < 4; ++j) {
      int r = lr + j;
      lbuf[r][col] = acc[j] + bff2[col] + ly2[r][col];
    }
  }
  __syncthreads();
  { // LN3 stats
    int r = t >> 5, j = t & 31;
    float s1 = 0.f, s2 = 0.f;
    #pragma unroll
    for (int cc = 0; cc < 4; ++cc) { float v = lbuf[r][j * 4 + cc]; s1 += v; s2 += v * v; }
    #pragma unroll
    for (int off = 1; off < 32; off <<= 1) { s1 += __shfl_xor(s1, off); s2 += __shfl_xor(s2, off); }
    if (j == 0) {
      float m = s1 * (1.f / 128.f);
      float var = s2 * (1.f / 128.f) - m * m;
      lmean[r] = m; lrstd[r] = rsqrtf(var + 1e-5f);
    }
  }
  __syncthreads();
  #pragma unroll
  for (int i = 0; i < 4; ++i) {   // in-place normalize (each elem owned by one thread)
    int idx = i * 512 + t;
    int r = idx >> 7, c = idx & 127;
    lbuf[r][c] = (lbuf[r][c] - lmean[r]) * lrstd[r] * ln3s[c] + ln3b[c];
  }
  __syncthreads();
  // ---- head: wave w -> coltile w; dx; masked update; stash x_new in ly2 ----
  #pragma unroll
  for (int kt = 0; kt < 4; ++kt)
    a4[kt] = afrag_f32(&lbuf[l & 15][kt * 32 + (l >> 4) * 8]);
  {
    f32x4 acc = (f32x4){0.f,0.f,0.f,0.f};
    const bf16x8* B = (const bf16x8*)pHead;
    #pragma unroll
    for (int kt = 0; kt < 4; ++kt)
      acc = __builtin_amdgcn_mfma_f32_16x16x32_bf16(a4[kt], B[(w * 4 + kt) * 64 + l], acc, 0, 0, 0);
    int col = w * 16 + lc;
    #pragma unroll
    for (int j = 0; j < 4; ++j) {
      int r = lr + j;
      size_t n = base + r;
      float dx = acc[j] + bhead[col];
      float xn = xres[j] + dx * lmask[r];
      xout[n * 128 + col] = xn;
      ly2[r][col] = xn;
    }
  }
  // ---- tail: next step's pe + LN1 + qkv GEMM (skipped on last step) ----
  if (s + 1 < *steps) {
    __syncthreads();
    if (t < 32) { int r = t >> 1, c = 126 + (t & 1); ly2[r][c] = pe_val(base + r, c); }
    __syncthreads();
    { // LN1 stats
      int r = t >> 5, j = t & 31;
      float s1 = 0.f, s2 = 0.f;
      #pragma unroll
      for (int cc = 0; cc < 4; ++cc) { float v = ly2[r][j * 4 + cc]; s1 += v; s2 += v * v; }
      #pragma unroll
      for (int off = 1; off < 32; off <<= 1) { s1 += __shfl_xor(s1, off); s2 += __shfl_xor(s2, off); }
      if (j == 0) {
        float m = s1 * (1.f / 128.f);
        float var = s2 * (1.f / 128.f) - m * m;
        lmean[r] = m; lrstd[r] = rsqrtf(var + 1e-5f);
      }
    }
    __syncthreads();
    #pragma unroll
    for (int i = 0; i < 4; ++i) {
      int idx = i * 512 + t;
      int r = idx >> 7, c = idx & 127;
      lbuf[r][c] = (ly2[r][c] - lmean[r]) * lrstd[r] * ln1s[c] + ln1b[c];
    }
    __syncthreads();
    #pragma unroll
    for (int kt = 0; kt < 4; ++kt)
      a4[kt] = afrag_f32(&lbuf[l & 15][kt * 32 + (l >> 4) * 8]);
    const bf16x8* B = (const bf16x8*)pQkv;
    #pragma unroll
    for (int q = 0; q < 3; ++q) {
      f32x4 acc = (f32x4){0.f,0.f,0.f,0.f};
      int nt = w * 3 + q;
      #pragma unroll
      for (int kt = 0; kt < 4; ++kt)
        acc = __builtin_amdgcn_mfma_f32_16x16x32_bf16(a4[kt], B[(nt * 4 + kt) * 64 + l], acc, 0, 0, 0);
      int col = nt * 16 + lc;
      #pragma unroll
      for (int j = 0; j < 4; ++j)
        qkvN[(size_t)(base + lr + j) * 384 + col] = f2bf(acc[j]);
    }
  }
}

extern "C" void kernel_launch(void* const* d_in, const int* in_sizes, int n_in,
                              void* d_out, int out_size, void* d_ws, size_t ws_size,
                              hipStream_t stream) {
  const float* x0   = (const float*)d_in[0];
  const float* Wqkv = (const float*)d_in[1];
  const float* Wout = (const float*)d_in[2];
  const float* bout = (const float*)d_in[3];
  const float* ln1s = (const float*)d_in[4];
  const float* ln1b = (const float*)d_in[5];
  const float* Wff1 = (const float*)d_in[6];
  const float* bff1 = (const float*)d_in[7];
  const float* Wff2 = (const float*)d_in[8];
  const float* bff2 = (const float*)d_in[9];
  const float* ln2s = (const float*)d_in[10];
  const float* ln2b = (const float*)d_in[11];
  const float* ln3s = (const float*)d_in[12];
  const float* ln3b = (const float*)d_in[13];
  const float* Whead= (const float*)d_in[14];
  const float* bhead= (const float*)d_in[15];
  const int*   steps= (const int*)d_in[16];
  float* out = (float*)d_out;

  unsigned short* qkvA = (unsigned short*)d_ws;          // N*384 bf16
  unsigned short* qkvB = qkvA + (size_t)NCELL * 384;     // N*384 bf16
  unsigned short* pQkv = qkvB + (size_t)NCELL * 384;
  unsigned short* pOut = pQkv + 128 * 384;
  unsigned short* pFF1 = pOut + 128 * 128;
  unsigned short* pFF2 = pFF1 + 128 * 512;
  unsigned short* pHead= pFF2 + 512 * 128;

  packAll<<<dim3(104), dim3(256), 0, stream>>>(Wqkv, Wout, Wff1, Wff2, Whead,
                                               pQkv, pOut, pFF1, pFF2, pHead);
  nca_k1<<<dim3(864), dim3(256), 0, stream>>>(x0, ln1s, ln1b, pQkv, qkvA, steps, 0);
  // s=0: read qkvA, write next-step qkvB; s=1: read qkvB (tail skipped)
  nca_kA<<<dim3(864), dim3(512), 0, stream>>>(qkvA, qkvB, pQkv, pOut, bout,
                                              ln1s, ln1b, ln2s, ln2b, pFF1, bff1,
                                              pFF2, bff2, ln3s, ln3b, pHead, bhead,
                                              x0, out, steps, 0);
  nca_kA<<<dim3(864), dim3(512), 0, stream>>>(qkvB, qkvA, pQkv, pOut, bout,
                                              ln1s, ln1b, ln2s, ln2b, pFF1, bff1,
                                              pFF2, bff2, ln3s, ln3b, pHead, bhead,
                                              out, out, steps, 1);
}